// Round 4
// baseline (223.978 us; speedup 1.0000x reference)
//
#include <hip/hip_runtime.h>

// Problem constants: B=4, C=3, H=512, W=960, K2=16 -> K=4
#define BB 4
#define CC 3
#define HH 512
#define WW 960
#define HW (HH * WW)

// Persistent blocks: each 256-thread block processes 4 vertically-consecutive
// 64x4 tiles, sliding a 28-row staged window through LDS.
#define TW 64
#define TH 4
#define NTX (WW / TW)            // 15
#define NTY (HH / TH)            // 128
#define TPB 4                    // tiles per block
#define NTYC (NTY / TPB)         // 32
#define NBLK (BB * NTX * NTYC)   // 1920 (% 8 == 0 for XCD swizzle)

// Staged window: rows y00-5 .. y00+22 (28), cols x0-8..x0+71 (80), 3 ch.
// Row = 61 chunks (60 data + 1 pad) = 244 floats. 244 mod 32 = 20 ->
// row-deltas k=1..7 land on distinct banks (decorrelates floor(fy) jitter).
// DMA rounds are exactly 256 full-exec chunks; pad/overflow chunks read
// duplicate valid sources and land inside the row-pad / spare region.
#define CHUNKS_PER_ROW 61
#define RSTRIDE 244
#define ROWS_TOT 28
#define LDS_CHUNKS 1792                 // 7 rounds x 256 (>= 28*61 = 1708)
#define LDS_FLOATS (LDS_CHUNKS * 4)     // 7168 floats = 28672 B -> 5 blocks/CU

typedef __attribute__((address_space(1))) const unsigned int gu32;
typedef __attribute__((address_space(3))) unsigned int lu32;

__global__ __launch_bounds__(256)
void filter_interp_kernel(const float* __restrict__ inp,
                          const float* __restrict__ flow,
                          const float* __restrict__ filt,
                          float* __restrict__ out) {
    __shared__ float lds[LDS_FLOATS];

    // Bijective XCD-aware swizzle; tyc-fastest -> vertical strips per XCD.
    const int bid = blockIdx.x;
    const int lid = (bid & 7) * (NBLK / 8) + (bid >> 3);
    const int b   = lid / (NTX * NTYC);
    const int rr  = lid - b * (NTX * NTYC);
    const int tx  = rr / NTYC;
    const int tyc = rr - tx * NTYC;
    const int x0  = tx * TW;
    const int y00 = tyc * (TH * TPB);   // first tile's y-origin

    const int tid  = threadIdx.x;
    const int wave = tid >> 6;
    const int lx   = tid & 63;
    const int x    = x0 + lx;

    const float* ibase = inp  + (size_t)b * CC * HW;
    const float* fbase = filt + (size_t)b * 16 * HW;
    const float* flbx  = flow + (size_t)(b * 2 + 0) * HW;
    const float* flby  = flow + (size_t)(b * 2 + 1) * HW;
    float*       obase = out  + (size_t)b * CC * HW;

    const bool interior = (tx > 0) && (tx < NTX - 1);

    // One 256-chunk full-exec DMA round. Chunk c -> staged row c/61,
    // row-chunk c%61 (60,61 = pad: duplicate source, never read).
    auto stage_round = [&](int u) {
        const int c   = u * 256 + tid;
        const int row = c / CHUNKS_PER_ROW;          // up to 29; grow clamps
        const int cc  = c - row * CHUNKS_PER_ROW;
        int ch, t4;
        if (cc < 60) { ch = cc / 20; t4 = cc - ch * 20; }
        else         { ch = 2;       t4 = 19; }      // pad: dup source
        const int grow = min(max(y00 - 5 + row, 0), HH - 1);
        const float* src = ibase + (size_t)ch * HW +
                           (size_t)grow * WW + (x0 - 8 + t4 * 4);
        lu32* dst = (lu32*)(void*)&lds[(u * 256 + wave * 64) * 4];
        __builtin_amdgcn_global_load_lds((gu32*)(const void*)src, dst, 16, 0, 0);
    };

    // Scalar staging for x-edge blocks (per-column clamp baked into slots).
    auto stage_scalar = [&](int r0, int nr) {
        const int total = nr * 240;
        for (int e = 0; e * 256 < total; ++e) {
            const int idx = e * 256 + tid;
            if (idx < total) {
                const int r   = idx / 240;
                const int col = idx - r * 240;       // ch*80 + t
                const int ch  = col / 80;
                const int t   = col - ch * 80;
                const int grow = min(max(y00 - 5 + r0 + r, 0), HH - 1);
                const int gcol = min(max(x0 - 8 + t, 0), WW - 1);
                lds[(r0 + r) * RSTRIDE + col] =
                    ibase[(size_t)ch * HW + (size_t)grow * WW + gcol];
            }
        }
    };

    // Prefetch next tile's flow + 16 filter taps into registers.
    auto load_pf = [&](int t, float* f, float& pfx, float& pfy, int& prem) {
        const int y   = y00 + t * TH + wave;
        const int rem = y * WW + x;
        prem = rem;
        pfx = flbx[rem];
        pfy = flby[rem];
        const float* fp = fbase + rem;
#pragma unroll
        for (int k = 0; k < 16; ++k) f[k] = fp[(size_t)k * HW];
    };

    auto compute_store = [&](int t, const float* f, float fx, float fy, int rem) {
        const int y   = y00 + t * TH + wave;
        const int y0t = y00 + t * TH;

        float acc0 = 0.0f, acc1 = 0.0f, acc2 = 0.0f;

        const float x2 = (float)x + fx;
        const float y2 = (float)y + fy;
        const bool valid = (x2 >= 0.0f) && (x2 <= (float)(WW - 1)) &&
                           (y2 >= 0.0f) && (y2 <= (float)(HH - 1)) &&
                           (fabsf(fx) < (float)WW * 0.5f) &&
                           (fabsf(fy) < (float)HH * 0.5f);
        if (valid) {
            const int ix = (int)floorf(x2);
            const int iy = (int)floorf(y2);
            const float alpha = x2 - (float)ix;
            const float beta  = y2 - (float)iy;

            const float wTL = (1.0f - alpha) * (1.0f - beta);
            const float wTR = alpha * (1.0f - beta);
            const float wBL = (1.0f - alpha) * beta;
            const float wBR = alpha * beta;

            float Wm[5][5];
#pragma unroll
            for (int j = 0; j < 5; ++j)
#pragma unroll
                for (int i = 0; i < 5; ++i) Wm[j][i] = 0.0f;
#pragma unroll
            for (int dj = 0; dj < 4; ++dj) {
#pragma unroll
                for (int di = 0; di < 4; ++di) {
                    const float fv = f[dj * 4 + di];
                    Wm[dj][di]         += fv * wTL;
                    Wm[dj][di + 1]     += fv * wTR;
                    Wm[dj + 1][di]     += fv * wBL;
                    Wm[dj + 1][di + 1] += fv * wBR;
                }
            }

            const int ixL0 = ix - 1;
            const int iyT0 = iy - 1;
            const int cs = ixL0 - (x0 - 8);           // col slot in window
            const int rs = iyT0 - (y0t - 5);          // row slot rel. to tile

            if ((unsigned)rs <= 11u && (unsigned)cs <= 75u) {
                // Fast path: b64 gather from staged window. Absolute row slot
                // = rs + 4t (0..27, no wrap). Weight row barrel-shift by cs&1.
                const int o  = cs & 1;
                const int e0 = cs - o;
                const float* lbase = lds + (rs + t * TH) * RSTRIDE + e0;
#pragma unroll
                for (int j = 0; j < 5; ++j) {
                    const float* lr = lbase + j * RSTRIDE;
                    const float w0 = o ? 0.0f     : Wm[j][0];
                    const float w1 = o ? Wm[j][0] : Wm[j][1];
                    const float w2 = o ? Wm[j][1] : Wm[j][2];
                    const float w3 = o ? Wm[j][2] : Wm[j][3];
                    const float w4 = o ? Wm[j][3] : Wm[j][4];
                    const float w5 = o ? Wm[j][4] : 0.0f;

                    const float2 a0 = *(const float2*)(lr);
                    const float2 a1 = *(const float2*)(lr + 2);
                    const float2 a2 = *(const float2*)(lr + 4);
                    acc0 += a0.x * w0 + a0.y * w1 + a1.x * w2 +
                            a1.y * w3 + a2.x * w4 + a2.y * w5;

                    const float2 b0 = *(const float2*)(lr + 80);
                    const float2 b1 = *(const float2*)(lr + 82);
                    const float2 b2 = *(const float2*)(lr + 84);
                    acc1 += b0.x * w0 + b0.y * w1 + b1.x * w2 +
                            b1.y * w3 + b2.x * w4 + b2.y * w5;

                    const float2 c0 = *(const float2*)(lr + 160);
                    const float2 c1 = *(const float2*)(lr + 162);
                    const float2 c2 = *(const float2*)(lr + 164);
                    acc2 += c0.x * w0 + c0.y * w1 + c1.x * w2 +
                            c1.y * w3 + c2.x * w4 + c2.y * w5;
                }
            } else {
                // Rare fallback: scalar clamped global gathers.
                int R[5], S[5];
#pragma unroll
                for (int j = 0; j < 5; ++j) R[j] = min(max(iyT0 + j, 0), HH - 1);
#pragma unroll
                for (int i = 0; i < 5; ++i) S[i] = min(max(ixL0 + i, 0), WW - 1);
#pragma unroll
                for (int j = 0; j < 5; ++j) {
                    const float* r0p = ibase + (size_t)R[j] * WW;
#pragma unroll
                    for (int i = 0; i < 5; ++i) {
                        const float w = Wm[j][i];
                        const size_t oo = (size_t)S[i];
                        acc0 += r0p[oo] * w;
                        acc1 += r0p[HW + oo] * w;
                        acc2 += r0p[2 * (size_t)HW + oo] * w;
                    }
                }
            }
        }

        out[(size_t)0]; // no-op keep-alive guard (optimized away)
        obase[rem]            = acc0;
        obase[rem + HW]       = acc1;
        obase[rem + 2 * HW]   = acc2;
    };

    // ---- Pipeline ----
    // Prologue: stage rows 0..20ish (chunks 0..1279 cover rows 0..19 fully,
    // needed by tiles 0 and 1) + tile-0 flow/filter prefetch.
    if (interior) {
        stage_round(0); stage_round(1); stage_round(2);
        stage_round(3); stage_round(4);
    } else {
        stage_scalar(0, 20);
    }

    float fA[16], fB[16];
    float fxA, fyA, fxB, fyB;
    int remA, remB;
    load_pf(0, fA, fxA, fyA, remA);

    __syncthreads();                      // drains prologue DMA + tile-0 regs
    if (interior) stage_round(5);         // rows ~21..25 (for tile 2)
    else          stage_scalar(20, 4);
    load_pf(1, fB, fxB, fyB, remB);       // flies during compute(0)
    compute_store(0, fA, fxA, fyA, remA);

    __syncthreads();                      // drains round 5 + tile-1 regs
    if (interior) stage_round(6);         // rows ~25..27 (for tile 3)
    else          stage_scalar(24, 4);
    load_pf(2, fA, fxA, fyA, remA);
    compute_store(1, fB, fxB, fyB, remB);

    __syncthreads();                      // drains round 6 + tile-2 regs
    load_pf(3, fB, fxB, fyB, remB);
    compute_store(2, fA, fxA, fyA, remA);

    // No barrier needed: no LDS writes after round 6 (drained above).
    compute_store(3, fB, fxB, fyB, remB);
}

extern "C" void kernel_launch(void* const* d_in, const int* in_sizes, int n_in,
                              void* d_out, int out_size, void* d_ws, size_t ws_size,
                              hipStream_t stream) {
    const float* teninput  = (const float*)d_in[0];
    const float* tenflow   = (const float*)d_in[1];
    const float* tenfilter = (const float*)d_in[2];
    float* out = (float*)d_out;

    filter_interp_kernel<<<NBLK, 256, 0, stream>>>(teninput, tenflow, tenfilter, out);
}